// Round 1
// baseline (380.185 us; speedup 1.0000x reference)
//
#include <hip/hip_runtime.h>

#define D_DIM 4096
#define N_DIM 1024
#define NNZ_F 131072
#define K_F 4

// ---------- tiled transpose: in [R, C] -> out [C, R] ----------
__global__ __launch_bounds__(256) void transpose_k(const float* __restrict__ in,
                                                   float* __restrict__ out,
                                                   int R, int C) {
    __shared__ float tile[32][33];
    int c0 = blockIdx.x * 32, r0 = blockIdx.y * 32;
    int tx = threadIdx.x, ty = threadIdx.y;   // block (32, 8)
#pragma unroll
    for (int i = ty; i < 32; i += 8)
        tile[i][tx] = in[(size_t)(r0 + i) * C + c0 + tx];
    __syncthreads();
#pragma unroll
    for (int i = ty; i < 32; i += 8)
        out[(size_t)(c0 + i) * R + r0 + tx] = tile[tx][i];
}

// ---------- tiled transpose + bias: in [R=D, C=N] -> out [N, D], out[n,d]=in[d,n]+bias[d]
__global__ __launch_bounds__(256) void transpose_bias_k(const float* __restrict__ in,
                                                        float* __restrict__ out,
                                                        const float* __restrict__ bias,
                                                        int R, int C) {
    __shared__ float tile[32][33];
    int c0 = blockIdx.x * 32, r0 = blockIdx.y * 32;
    int tx = threadIdx.x, ty = threadIdx.y;
#pragma unroll
    for (int i = ty; i < 32; i += 8)
        tile[i][tx] = in[(size_t)(r0 + i) * C + c0 + tx];
    __syncthreads();
    float b = bias[r0 + tx];
#pragma unroll
    for (int i = ty; i < 32; i += 8)
        out[(size_t)(c0 + i) * R + r0 + tx] = tile[tx][i] + b;
}

// ---------- CSR build ----------
__global__ __launch_bounds__(256) void count_k(const int* __restrict__ rows,
                                               int* __restrict__ counts) {
    int j = blockIdx.x * 256 + threadIdx.x;
    if (j < NNZ_F) atomicAdd(&counts[rows[j]], 1);
}

__global__ __launch_bounds__(256) void scan_k(const int* __restrict__ counts,
                                              int* __restrict__ row_ptr,
                                              int* __restrict__ cursor) {
    // single block, 256 threads, exclusive scan of counts[D_DIM]
    __shared__ int s_sums[256];
    int tid = threadIdx.x;
    const int per = D_DIM / 256;   // 16
    int base = tid * per;
    int v[per];
    int local = 0;
#pragma unroll
    for (int i = 0; i < per; ++i) { v[i] = counts[base + i]; local += v[i]; }
    s_sums[tid] = local;
    __syncthreads();
    for (int off = 1; off < 256; off <<= 1) {
        int t = 0;
        if (tid >= off) t = s_sums[tid - off];
        __syncthreads();
        s_sums[tid] += t;
        __syncthreads();
    }
    int excl = (tid == 0) ? 0 : s_sums[tid - 1];
#pragma unroll
    for (int i = 0; i < per; ++i) {
        row_ptr[base + i] = excl;
        cursor[base + i]  = excl;
        excl += v[i];
    }
    if (tid == 255) row_ptr[D_DIM] = excl;
}

__global__ __launch_bounds__(256) void scatter_k(const int* __restrict__ rows,
                                                 const int* __restrict__ cols,
                                                 const float* __restrict__ vals,
                                                 int* __restrict__ cursor,
                                                 int* __restrict__ csr_col,
                                                 float* __restrict__ csr_val) {
    int j = blockIdx.x * 256 + threadIdx.x;
    if (j < NNZ_F) {
        int r = rows[j];
        int p = atomicAdd(&cursor[r], 1);
        csr_col[p] = cols[j];
        csr_val[p] = vals[j];
    }
}

// ---------- CSR spmm: Y[r, :] = sum_j v_j * X[c_j, :], layout [D, N] ----------
__global__ __launch_bounds__(256) void spmm_k(const int* __restrict__ row_ptr,
                                              const int* __restrict__ csr_col,
                                              const float* __restrict__ csr_val,
                                              const float4* __restrict__ X,
                                              float4* __restrict__ Y) {
    const int r = blockIdx.x;
    const int tid = threadIdx.x;
    const int start = row_ptr[r];
    const int end = row_ptr[r + 1];
    const int NV = N_DIM / 4;   // 256 float4 per row

    __shared__ int   s_col[256];
    __shared__ float s_val[256];

    float4 acc = {0.f, 0.f, 0.f, 0.f};
    for (int base = start; base < end; base += 256) {
        int cnt = end - base;
        if (cnt > 256) cnt = 256;
        if (tid < cnt) {
            s_col[tid] = csr_col[base + tid];
            s_val[tid] = csr_val[base + tid];
        }
        __syncthreads();
#pragma unroll 4
        for (int j = 0; j < cnt; ++j) {
            const float v = s_val[j];
            const int   c = s_col[j];
            const float4 x = X[(size_t)c * NV + tid];
            acc.x += v * x.x;
            acc.y += v * x.y;
            acc.z += v * x.z;
            acc.w += v * x.w;
        }
        __syncthreads();
    }
    Y[(size_t)r * NV + tid] = acc;
}

extern "C" void kernel_launch(void* const* d_in, const int* in_sizes, int n_in,
                              void* d_out, int out_size, void* d_ws, size_t ws_size,
                              hipStream_t stream) {
    const float* U    = (const float*)d_in[0];
    const float* bias = (const float*)d_in[1];
    const float* vals = (const float*)d_in[2];
    const int*   rows = (const int*)d_in[3];
    const int*   cols = (const int*)d_in[4];
    float* out = (float*)d_out;

    char* ws = (char*)d_ws;
    size_t off = 0;
    float* bufA = (float*)(ws + off);  off += (size_t)D_DIM * N_DIM * 4;   // 16 MB
    int* counts  = (int*)(ws + off);   off += (size_t)D_DIM * 4;
    int* row_ptr = (int*)(ws + off);   off += (size_t)(D_DIM + 1) * 4;
    off = (off + 15) & ~(size_t)15;
    int* cursor  = (int*)(ws + off);   off += (size_t)D_DIM * 4;
    int*   csr_col = (int*)(ws + off); off += (size_t)NNZ_F * 4;
    float* csr_val = (float*)(ws + off); off += (size_t)NNZ_F * 4;
    float* bufB = (float*)d_out;  // reuse output buffer as ping-pong intermediate

    dim3 tb(32, 8);

    // U [N, D] -> bufA = U^T [D, N]
    transpose_k<<<dim3(D_DIM / 32, N_DIM / 32), tb, 0, stream>>>(U, bufA, N_DIM, D_DIM);

    float* src = bufA;
    float* dst = bufB;
    for (int i = K_F - 1; i >= 0; --i) {
        hipMemsetAsync(counts, 0, D_DIM * 4, stream);
        count_k<<<NNZ_F / 256, 256, 0, stream>>>(rows + (size_t)i * NNZ_F, counts);
        scan_k<<<1, 256, 0, stream>>>(counts, row_ptr, cursor);
        scatter_k<<<NNZ_F / 256, 256, 0, stream>>>(rows + (size_t)i * NNZ_F,
                                                   cols + (size_t)i * NNZ_F,
                                                   vals + (size_t)i * NNZ_F,
                                                   cursor, csr_col, csr_val);
        spmm_k<<<D_DIM, 256, 0, stream>>>(row_ptr, csr_col, csr_val,
                                          (const float4*)src, (float4*)dst);
        float* t = src; src = dst; dst = t;
    }
    // after 4 factors (even count), result is back in bufA == src
    // final: out[n, d] = src[d, n] + bias[d]
    transpose_bias_k<<<dim3(N_DIM / 32, D_DIM / 32), tb, 0, stream>>>(src, out, bias,
                                                                      D_DIM, N_DIM);
}

// Round 2
// 188.458 us; speedup vs baseline: 2.0173x; 2.0173x over previous
//
#include <hip/hip_runtime.h>

#define D_DIM 4096
#define N_DIM 1024
#define NNZ_F 131072
#define K_F 4
#define NV (N_DIM / 4)     // 256 float4 per row
#define NCHUNK 8           // one column-chunk per XCD
#define CW (NV / NCHUNK)   // 32 float4 (128 floats, 512B) per chunk
#define RPB 8              // rows per block (8 rows x 32 lanes = 256 thr)
#define MAXE 512           // LDS staging capacity for CSR entries per block

// ---------- tiled transpose: in [R, C] -> out [C, R] ----------
__global__ __launch_bounds__(256) void transpose_k(const float* __restrict__ in,
                                                   float* __restrict__ out,
                                                   int R, int C) {
    __shared__ float tile[32][33];
    int c0 = blockIdx.x * 32, r0 = blockIdx.y * 32;
    int tx = threadIdx.x, ty = threadIdx.y;   // block (32, 8)
#pragma unroll
    for (int i = ty; i < 32; i += 8)
        tile[i][tx] = in[(size_t)(r0 + i) * C + c0 + tx];
    __syncthreads();
#pragma unroll
    for (int i = ty; i < 32; i += 8)
        out[(size_t)(c0 + i) * R + r0 + tx] = tile[tx][i];
}

// ---------- tiled transpose + bias: in [D, N] -> out [N, D] with +bias[d] ----------
__global__ __launch_bounds__(256) void transpose_bias_k(const float* __restrict__ in,
                                                        float* __restrict__ out,
                                                        const float* __restrict__ bias,
                                                        int R, int C) {
    __shared__ float tile[32][33];
    int c0 = blockIdx.x * 32, r0 = blockIdx.y * 32;
    int tx = threadIdx.x, ty = threadIdx.y;
#pragma unroll
    for (int i = ty; i < 32; i += 8)
        tile[i][tx] = in[(size_t)(r0 + i) * C + c0 + tx];
    __syncthreads();
    float b = bias[r0 + tx];
#pragma unroll
    for (int i = ty; i < 32; i += 8)
        out[(size_t)(c0 + i) * R + r0 + tx] = tile[tx][i] + b;
}

// ---------- CSR build (nf factors in one shot) ----------
__global__ __launch_bounds__(256) void count_all_k(const int* __restrict__ rows,
                                                   int* __restrict__ counts, int npb) {
    int f = blockIdx.x / npb;
    int j = (blockIdx.x % npb) * 256 + threadIdx.x;
    atomicAdd(&counts[(size_t)f * D_DIM + rows[(size_t)f * NNZ_F + j]], 1);
}

__global__ __launch_bounds__(256) void scan_all_k(const int* __restrict__ counts_g,
                                                  int* __restrict__ row_ptr_g,
                                                  int* __restrict__ cursor_g) {
    int f = blockIdx.x;
    const int* counts = counts_g + (size_t)f * D_DIM;
    int* row_ptr = row_ptr_g + (size_t)f * (D_DIM + 1);
    int* cursor  = cursor_g + (size_t)f * D_DIM;

    __shared__ int s_sums[256];
    int tid = threadIdx.x;
    const int per = D_DIM / 256;   // 16
    int base = tid * per;
    int v[per];
    int local = 0;
#pragma unroll
    for (int i = 0; i < per; ++i) { v[i] = counts[base + i]; local += v[i]; }
    s_sums[tid] = local;
    __syncthreads();
    for (int off = 1; off < 256; off <<= 1) {
        int t = 0;
        if (tid >= off) t = s_sums[tid - off];
        __syncthreads();
        s_sums[tid] += t;
        __syncthreads();
    }
    int excl = (tid == 0) ? 0 : s_sums[tid - 1];
#pragma unroll
    for (int i = 0; i < per; ++i) {
        row_ptr[base + i] = excl;
        cursor[base + i]  = excl;
        excl += v[i];
    }
    if (tid == 255) row_ptr[D_DIM] = excl;
}

__global__ __launch_bounds__(256) void scatter_all_k(const int* __restrict__ rows,
                                                     const int* __restrict__ cols,
                                                     const float* __restrict__ vals,
                                                     int* __restrict__ cursor,
                                                     int* __restrict__ csr_col,
                                                     float* __restrict__ csr_val, int npb) {
    int f = blockIdx.x / npb;
    int j = (blockIdx.x % npb) * 256 + threadIdx.x;
    int r = rows[(size_t)f * NNZ_F + j];
    int p = atomicAdd(&cursor[(size_t)f * D_DIM + r], 1);
    csr_col[(size_t)f * NNZ_F + p] = cols[(size_t)f * NNZ_F + j];
    csr_val[(size_t)f * NNZ_F + p] = vals[(size_t)f * NNZ_F + j];
}

// ---------- chunked CSR spmm: Y[r, chunk] = sum_j v_j * X[c_j, chunk] ----------
// grid = (D_DIM/RPB) * NCHUNK blocks; chunk = blockIdx & 7 -> XCD-affine, so each
// XCD's L2 holds only its 2MB column slice of X.
__global__ __launch_bounds__(256) void spmm_chunk_k(const int* __restrict__ row_ptr,
                                                    const int* __restrict__ csr_col,
                                                    const float* __restrict__ csr_val,
                                                    const float4* __restrict__ X,
                                                    float4* __restrict__ Y) {
    const int chunk = blockIdx.x & (NCHUNK - 1);
    const int rg    = blockIdx.x >> 3;
    const int r0    = rg * RPB;
    const int sub   = threadIdx.x >> 5;       // row within group: 0..7
    const int lane  = threadIdx.x & 31;       // float4 lane within chunk
    const int cbase = chunk * CW;
    const int r     = r0 + sub;

    __shared__ int   s_ptr[RPB + 1];
    __shared__ int   s_col[MAXE];
    __shared__ float s_val[MAXE];

    if (threadIdx.x <= RPB) s_ptr[threadIdx.x] = row_ptr[r0 + threadIdx.x];
    __syncthreads();
    const int base  = s_ptr[0];
    const int total = s_ptr[RPB] - base;
    const int start = s_ptr[sub] - base;
    const int end_  = s_ptr[sub + 1] - base;

    float4 acc = {0.f, 0.f, 0.f, 0.f};
    for (int cb2 = 0; cb2 < total; cb2 += MAXE) {
        int cnt = total - cb2;
        if (cnt > MAXE) cnt = MAXE;
        for (int t = threadIdx.x; t < cnt; t += 256) {
            s_col[t] = csr_col[base + cb2 + t];
            s_val[t] = csr_val[base + cb2 + t];
        }
        __syncthreads();
        int js = start > cb2 ? start : cb2;
        int je = end_ < cb2 + cnt ? end_ : cb2 + cnt;
#pragma unroll 4
        for (int j = js; j < je; ++j) {
            const float v = s_val[j - cb2];
            const int   c = s_col[j - cb2];
            const float4 x = X[(size_t)c * NV + cbase + lane];
            acc.x += v * x.x;
            acc.y += v * x.y;
            acc.z += v * x.z;
            acc.w += v * x.w;
        }
        __syncthreads();
    }
    Y[(size_t)r * NV + cbase + lane] = acc;
}

extern "C" void kernel_launch(void* const* d_in, const int* in_sizes, int n_in,
                              void* d_out, int out_size, void* d_ws, size_t ws_size,
                              hipStream_t stream) {
    const float* U    = (const float*)d_in[0];
    const float* bias = (const float*)d_in[1];
    const float* vals = (const float*)d_in[2];
    const int*   rows = (const int*)d_in[3];
    const int*   cols = (const int*)d_in[4];
    float* out = (float*)d_out;

    char* ws = (char*)d_ws;
    size_t off = 0;
    float* bufA = (float*)(ws + off);  off += (size_t)D_DIM * N_DIM * 4;   // 16 MB
    // batched CSR layout: need 4 factors' worth
    const size_t per_counts  = (size_t)D_DIM * 4;
    const size_t per_rowptr  = (size_t)(D_DIM + 1) * 4;
    const size_t per_csr     = (size_t)NNZ_F * 4;
    size_t need_batched = off + 4 * (per_counts * 2 + per_rowptr + per_csr * 2) + 256;
    const bool batched = ws_size >= need_batched;
    const int nf = batched ? K_F : 1;

    int* counts  = (int*)(ws + off);   off += per_counts * nf;
    int* row_ptr = (int*)(ws + off);   off += per_rowptr * nf;
    off = (off + 15) & ~(size_t)15;
    int* cursor  = (int*)(ws + off);   off += per_counts * nf;
    int*   csr_col = (int*)(ws + off); off += per_csr * nf;
    float* csr_val = (float*)(ws + off); off += per_csr * nf;
    float* bufB = (float*)d_out;  // reuse output buffer as ping-pong intermediate

    dim3 tb(32, 8);
    const int npb = NNZ_F / 256;  // blocks per factor for count/scatter

    // U [N, D] -> bufA = U^T [D, N]
    transpose_k<<<dim3(D_DIM / 32, N_DIM / 32), tb, 0, stream>>>(U, bufA, N_DIM, D_DIM);

    if (batched) {
        hipMemsetAsync(counts, 0, per_counts * K_F, stream);
        count_all_k<<<K_F * npb, 256, 0, stream>>>(rows, counts, npb);
        scan_all_k<<<K_F, 256, 0, stream>>>(counts, row_ptr, cursor);
        scatter_all_k<<<K_F * npb, 256, 0, stream>>>(rows, cols, vals, cursor,
                                                     csr_col, csr_val, npb);
    }

    float* src = bufA;
    float* dst = bufB;
    for (int i = K_F - 1; i >= 0; --i) {
        const int*   rp; const int* cc; const float* cv;
        if (batched) {
            rp = row_ptr + (size_t)i * (D_DIM + 1);
            cc = csr_col + (size_t)i * NNZ_F;
            cv = csr_val + (size_t)i * NNZ_F;
        } else {
            hipMemsetAsync(counts, 0, per_counts, stream);
            count_all_k<<<npb, 256, 0, stream>>>(rows + (size_t)i * NNZ_F, counts, npb);
            scan_all_k<<<1, 256, 0, stream>>>(counts, row_ptr, cursor);
            scatter_all_k<<<npb, 256, 0, stream>>>(rows + (size_t)i * NNZ_F,
                                                   cols + (size_t)i * NNZ_F,
                                                   vals + (size_t)i * NNZ_F,
                                                   cursor, csr_col, csr_val, npb);
            rp = row_ptr; cc = csr_col; cv = csr_val;
        }
        spmm_chunk_k<<<(D_DIM / RPB) * NCHUNK, 256, 0, stream>>>(
            rp, cc, cv, (const float4*)src, (float4*)dst);
        float* t = src; src = dst; dst = t;
    }
    // after 4 factors (even count), result is back in bufA == src
    transpose_bias_k<<<dim3(N_DIM / 32, D_DIM / 32), tb, 0, stream>>>(src, out, bias,
                                                                      D_DIM, N_DIM);
}

// Round 3
// 154.738 us; speedup vs baseline: 2.4570x; 1.2179x over previous
//
#include <hip/hip_runtime.h>

#define D_DIM 4096
#define N_DIM 1024
#define NNZ_F 131072
#define K_F 4
#define NV (N_DIM / 4)     // 256 float4 per row
#define NCHUNK 8           // one column-chunk per XCD
#define CW (NV / NCHUNK)   // 32 float4 (128 floats, 512B) per chunk
#define RPB 8              // rows per block (8 rows x 32 lanes = 256 thr)
#define MAXE 512           // LDS staging capacity for CSR entries per block

#define T_TILES ((D_DIM / 64) * (N_DIM / 64))   // 64 * 16 = 1024 transpose tiles

// ---------- fused: transpose U [N,D] -> UT [D,N]  (+)  per-factor CSR count+scan ----------
// grid = T_TILES + K_F blocks, 1024 threads.
__global__ __launch_bounds__(1024) void fused_t_build_k(const float* __restrict__ in,
                                                        float* __restrict__ out,
                                                        const int* __restrict__ rows,
                                                        int* __restrict__ row_ptr_g,
                                                        int* __restrict__ cursor_g) {
    __shared__ float smem[64 * 65];          // transpose tile OR 4096 int counters
    __shared__ int s_part[1024];
    const int tid = threadIdx.x;
    const int bid = blockIdx.x;

    if (bid < T_TILES) {
        // ---- transpose tile: 64x64 ----
        float (*tile)[65] = (float (*)[65])smem;
        const int gxi = bid & 63;            // D/64 = 64 tiles along D
        const int gyi = bid >> 6;            // N/64 = 16 tiles along N
        const int c0 = gxi * 64;             // offset in D
        const int r0 = gyi * 64;             // offset in N
        const int tx = tid & 63;
        const int ty = tid >> 6;             // 0..15
#pragma unroll
        for (int i = ty; i < 64; i += 16)
            tile[i][tx] = in[(size_t)(r0 + i) * D_DIM + c0 + tx];
        __syncthreads();
#pragma unroll
        for (int i = ty; i < 64; i += 16)
            out[(size_t)(c0 + i) * N_DIM + r0 + tx] = tile[tx][i];
        return;
    }

    // ---- CSR count + exclusive scan for factor f (one block per factor) ----
    const int f = bid - T_TILES;
    int* s_cnt = (int*)smem;                 // 4096 counters
#pragma unroll
    for (int k = 0; k < 4; ++k) s_cnt[tid + k * 1024] = 0;
    __syncthreads();

    const int4* rp4 = (const int4*)(rows + (size_t)f * NNZ_F);
#pragma unroll 4
    for (int it = 0; it < NNZ_F / 4096; ++it) {      // 32 iters
        int4 r4 = rp4[(size_t)it * 1024 + tid];
        atomicAdd(&s_cnt[r4.x], 1);
        atomicAdd(&s_cnt[r4.y], 1);
        atomicAdd(&s_cnt[r4.z], 1);
        atomicAdd(&s_cnt[r4.w], 1);
    }
    __syncthreads();

    const int c0v = s_cnt[tid * 4 + 0];
    const int c1v = s_cnt[tid * 4 + 1];
    const int c2v = s_cnt[tid * 4 + 2];
    const int c3v = s_cnt[tid * 4 + 3];
    const int part = c0v + c1v + c2v + c3v;
    s_part[tid] = part;
    __syncthreads();
    for (int off = 1; off < 1024; off <<= 1) {
        int v = (tid >= off) ? s_part[tid - off] : 0;
        __syncthreads();
        s_part[tid] += v;
        __syncthreads();
    }
    int excl = s_part[tid] - part;

    int* rp  = row_ptr_g + (size_t)f * (D_DIM + 1);
    int* cur = cursor_g + (size_t)f * D_DIM;
    int b = tid * 4;
    rp[b + 0] = excl; cur[b + 0] = excl; excl += c0v;
    rp[b + 1] = excl; cur[b + 1] = excl; excl += c1v;
    rp[b + 2] = excl; cur[b + 2] = excl; excl += c2v;
    rp[b + 3] = excl; cur[b + 3] = excl; excl += c3v;
    if (tid == 1023) rp[D_DIM] = NNZ_F;
}

// ---------- scatter all factors into CSR ----------
__global__ __launch_bounds__(1024) void scatter_all_k(const int* __restrict__ rows,
                                                      const int* __restrict__ cols,
                                                      const float* __restrict__ vals,
                                                      int* __restrict__ cursor,
                                                      int* __restrict__ csr_col,
                                                      float* __restrict__ csr_val) {
    const int f = blockIdx.x >> 7;                        // 128 blocks per factor
    const size_t j = (size_t)(blockIdx.x & 127) * 1024 + threadIdx.x;
    const size_t base = (size_t)f * NNZ_F;
    int r = rows[base + j];
    int p = atomicAdd(&cursor[(size_t)f * D_DIM + r], 1);
    csr_col[base + p] = cols[base + j];
    csr_val[base + p] = vals[base + j];
}

// ---------- chunked CSR spmm: Y[r, chunk] = sum_j v_j * X[c_j, chunk] ----------
// chunk = blockIdx & 7 -> XCD-affine; each XCD's L2 holds its 2MB column slice of X.
__global__ __launch_bounds__(256) void spmm_chunk_k(const int* __restrict__ row_ptr,
                                                    const int* __restrict__ csr_col,
                                                    const float* __restrict__ csr_val,
                                                    const float4* __restrict__ X,
                                                    float4* __restrict__ Y) {
    const int chunk = blockIdx.x & (NCHUNK - 1);
    const int rg    = blockIdx.x >> 3;
    const int r0    = rg * RPB;
    const int sub   = threadIdx.x >> 5;       // row within group: 0..7
    const int lane  = threadIdx.x & 31;       // float4 lane within chunk
    const int cbase = chunk * CW;
    const int r     = r0 + sub;

    __shared__ int   s_ptr[RPB + 1];
    __shared__ int   s_col[MAXE];
    __shared__ float s_val[MAXE];

    if (threadIdx.x <= RPB) s_ptr[threadIdx.x] = row_ptr[r0 + threadIdx.x];
    __syncthreads();
    const int base  = s_ptr[0];
    const int total = s_ptr[RPB] - base;
    const int start = s_ptr[sub] - base;
    const int end_  = s_ptr[sub + 1] - base;

    float4 acc = {0.f, 0.f, 0.f, 0.f};
    for (int cb2 = 0; cb2 < total; cb2 += MAXE) {
        int cnt = total - cb2;
        if (cnt > MAXE) cnt = MAXE;
        for (int t = threadIdx.x; t < cnt; t += 256) {
            s_col[t] = csr_col[base + cb2 + t];
            s_val[t] = csr_val[base + cb2 + t];
        }
        __syncthreads();
        int js = start > cb2 ? start : cb2;
        int je = end_ < cb2 + cnt ? end_ : cb2 + cnt;
#pragma unroll 4
        for (int j = js; j < je; ++j) {
            const float v = s_val[j - cb2];
            const int   c = s_col[j - cb2];
            const float4 x = X[(size_t)c * NV + cbase + lane];
            acc.x += v * x.x;
            acc.y += v * x.y;
            acc.z += v * x.z;
            acc.w += v * x.w;
        }
        __syncthreads();
    }
    Y[(size_t)r * NV + cbase + lane] = acc;
}

// ---------- tiled transpose + bias: in [D, N] -> out [N, D] with +bias[d] ----------
__global__ __launch_bounds__(256) void transpose_bias_k(const float* __restrict__ in,
                                                        float* __restrict__ out,
                                                        const float* __restrict__ bias) {
    __shared__ float tile[32][33];
    int c0 = blockIdx.x * 32, r0 = blockIdx.y * 32;   // c over N, r over D
    int tx = threadIdx.x, ty = threadIdx.y;
#pragma unroll
    for (int i = ty; i < 32; i += 8)
        tile[i][tx] = in[(size_t)(r0 + i) * N_DIM + c0 + tx];
    __syncthreads();
    float b = bias[r0 + tx];
#pragma unroll
    for (int i = ty; i < 32; i += 8)
        out[(size_t)(c0 + i) * D_DIM + r0 + tx] = tile[tx][i] + b;
}

extern "C" void kernel_launch(void* const* d_in, const int* in_sizes, int n_in,
                              void* d_out, int out_size, void* d_ws, size_t ws_size,
                              hipStream_t stream) {
    const float* U    = (const float*)d_in[0];
    const float* bias = (const float*)d_in[1];
    const float* vals = (const float*)d_in[2];
    const int*   rows = (const int*)d_in[3];
    const int*   cols = (const int*)d_in[4];
    float* out = (float*)d_out;

    char* ws = (char*)d_ws;
    size_t off = 0;
    float* bufA = (float*)(ws + off);  off += (size_t)D_DIM * N_DIM * 4;   // 16 MB
    int* row_ptr = (int*)(ws + off);   off += (size_t)K_F * (D_DIM + 1) * 4;
    off = (off + 15) & ~(size_t)15;
    int* cursor  = (int*)(ws + off);   off += (size_t)K_F * D_DIM * 4;
    int*   csr_col = (int*)(ws + off); off += (size_t)K_F * NNZ_F * 4;
    float* csr_val = (float*)(ws + off); off += (size_t)K_F * NNZ_F * 4;
    float* bufB = (float*)d_out;  // reuse output buffer as ping-pong intermediate

    // K1: transpose U -> bufA (1024 tiles) + CSR count/scan (4 blocks), fused
    fused_t_build_k<<<T_TILES + K_F, 1024, 0, stream>>>(U, bufA, rows, row_ptr, cursor);

    // K2: scatter all factors
    scatter_all_k<<<K_F * (NNZ_F / 1024), 1024, 0, stream>>>(rows, cols, vals, cursor,
                                                             csr_col, csr_val);

    // K3-K6: spmm chain (factor 3 first)
    float* src = bufA;
    float* dst = bufB;
    for (int i = K_F - 1; i >= 0; --i) {
        spmm_chunk_k<<<(D_DIM / RPB) * NCHUNK, 256, 0, stream>>>(
            row_ptr + (size_t)i * (D_DIM + 1),
            csr_col + (size_t)i * NNZ_F,
            csr_val + (size_t)i * NNZ_F,
            (const float4*)src, (float4*)dst);
        float* t = src; src = dst; dst = t;
    }

    // K7: final transpose + bias (src == bufA after 4 swaps)
    transpose_bias_k<<<dim3(N_DIM / 32, D_DIM / 32), dim3(32, 8), 0, stream>>>(src, out, bias);
}

// Round 4
// 141.929 us; speedup vs baseline: 2.6787x; 1.0902x over previous
//
#include <hip/hip_runtime.h>

#define D_DIM 4096
#define N_DIM 1024
#define NNZ_F 131072
#define K_F 4
#define NV4 (N_DIM / 4)    // 256 x (4-elem) slots per row
#define NCHUNK 8           // one column-chunk per XCD
#define CES (N_DIM / NCHUNK)   // 128 elements per chunk
#define CS4 (CES / 4)          // 32 4-elem slots per chunk
#define RPB 8              // rows per block (8 rows x 32 lanes = 256 thr)
#define MAXE 512           // LDS staging capacity for CSR entries per block

#define T_TILES ((D_DIM / 64) * (N_DIM / 64))   // 1024 transpose tiles

__device__ __forceinline__ unsigned short f2bf(float f) {
    union { float f; unsigned int u; } v; v.f = f;
    unsigned int r = v.u + 0x7fffu + ((v.u >> 16) & 1u);   // RNE, finite inputs
    return (unsigned short)(r >> 16);
}
__device__ __forceinline__ float bf2f(unsigned short h) {
    union { float f; unsigned int u; } v; v.u = ((unsigned int)h) << 16;
    return v.f;
}

// ---------- fused: transpose U [N,D] f32 -> UT [D,N] bf16  (+)  per-factor CSR count+scan
// grid = T_TILES + K_F blocks, 1024 threads.
__global__ __launch_bounds__(1024) void fused_t_build_k(const float* __restrict__ in,
                                                        unsigned short* __restrict__ outb,
                                                        const int* __restrict__ rows,
                                                        int* __restrict__ row_ptr_g,
                                                        int* __restrict__ cursor_g) {
    __shared__ int s_cnt[4 * D_DIM];          // 64 KB: 4 sub-histograms OR transpose tile
    __shared__ int s_part[1024];
    const int tid = threadIdx.x;
    const int bid = blockIdx.x;

    if (bid < T_TILES) {
        // ---- transpose tile: 64x64, f32 in -> bf16 out ----
        float (*tile)[65] = (float (*)[65])s_cnt;
        const int gxi = bid & 63;            // tile along D
        const int gyi = bid >> 6;            // tile along N
        const int c0 = gxi * 64;             // offset in D
        const int r0 = gyi * 64;             // offset in N
        const int tx = tid & 63;
        const int ty = tid >> 6;             // 0..15
#pragma unroll
        for (int i = ty; i < 64; i += 16)
            tile[i][tx] = in[(size_t)(r0 + i) * D_DIM + c0 + tx];
        __syncthreads();
        const int px = (tid & 31) * 2;       // pair of n-locals
        const int py = tid >> 5;             // 0..31
#pragma unroll
        for (int i = py; i < 64; i += 32) {
            ushort2 w;
            w.x = f2bf(tile[px][i]);
            w.y = f2bf(tile[px + 1][i]);
            *(ushort2*)&outb[(size_t)(c0 + i) * N_DIM + r0 + px] = w;
        }
        return;
    }

    // ---- CSR count + exclusive scan for factor f (one block per factor) ----
    const int f = bid - T_TILES;
    const int grp = (tid >> 8) & 3;          // 4 wave-groups, private histograms
#pragma unroll
    for (int k = 0; k < 16; ++k) s_cnt[tid + k * 1024] = 0;
    __syncthreads();

    int* h = s_cnt + grp * D_DIM;
    const int4* rp4 = (const int4*)(rows + (size_t)f * NNZ_F);
#pragma unroll 4
    for (int it = 0; it < NNZ_F / 4096; ++it) {      // 32 iters
        int4 r4 = rp4[(size_t)it * 1024 + tid];
        atomicAdd(&h[r4.x], 1);
        atomicAdd(&h[r4.y], 1);
        atomicAdd(&h[r4.z], 1);
        atomicAdd(&h[r4.w], 1);
    }
    __syncthreads();

    int c[4];
#pragma unroll
    for (int k = 0; k < 4; ++k)
        c[k] = s_cnt[tid * 4 + k] + s_cnt[D_DIM + tid * 4 + k]
             + s_cnt[2 * D_DIM + tid * 4 + k] + s_cnt[3 * D_DIM + tid * 4 + k];
    const int part = c[0] + c[1] + c[2] + c[3];
    s_part[tid] = part;
    __syncthreads();
    for (int off = 1; off < 1024; off <<= 1) {
        int v = (tid >= off) ? s_part[tid - off] : 0;
        __syncthreads();
        s_part[tid] += v;
        __syncthreads();
    }
    int excl = s_part[tid] - part;

    int* rp  = row_ptr_g + (size_t)f * (D_DIM + 1);
    int* cur = cursor_g + (size_t)f * D_DIM;
    int b = tid * 4;
#pragma unroll
    for (int k = 0; k < 4; ++k) {
        rp[b + k] = excl; cur[b + k] = excl; excl += c[k];
    }
    if (tid == 1023) rp[D_DIM] = NNZ_F;
}

// ---------- scatter all factors into CSR ----------
__global__ __launch_bounds__(1024) void scatter_all_k(const int* __restrict__ rows,
                                                      const int* __restrict__ cols,
                                                      const float* __restrict__ vals,
                                                      int* __restrict__ cursor,
                                                      int* __restrict__ csr_col,
                                                      float* __restrict__ csr_val) {
    const int f = blockIdx.x >> 7;                        // 128 blocks per factor
    const size_t j = (size_t)(blockIdx.x & 127) * 1024 + threadIdx.x;
    const size_t base = (size_t)f * NNZ_F;
    int r = rows[base + j];
    int p = atomicAdd(&cursor[(size_t)f * D_DIM + r], 1);
    csr_col[base + p] = cols[base + j];
    csr_val[base + p] = vals[base + j];
}

// ---------- chunked CSR spmm, bf16 input: Y[r,chunk] = sum_j v_j * X[c_j,chunk] ----------
// chunk = blockIdx & 7 -> XCD-affine; each XCD's L2 holds its 1MB bf16 column slice.
template <bool OUT_F32>
__global__ __launch_bounds__(256) void spmm_chunk_k(const int* __restrict__ row_ptr,
                                                    const int* __restrict__ csr_col,
                                                    const float* __restrict__ csr_val,
                                                    const ushort4* __restrict__ X,
                                                    void* __restrict__ Yv) {
    const int chunk = blockIdx.x & (NCHUNK - 1);
    const int rg    = blockIdx.x >> 3;
    const int r0    = rg * RPB;
    const int sub   = threadIdx.x >> 5;       // row within group: 0..7
    const int lane  = threadIdx.x & 31;       // 4-elem slot within chunk
    const int cb    = chunk * CS4;
    const int r     = r0 + sub;

    __shared__ int   s_ptr[RPB + 1];
    __shared__ int   s_col[MAXE];
    __shared__ float s_val[MAXE];

    if (threadIdx.x <= RPB) s_ptr[threadIdx.x] = row_ptr[r0 + threadIdx.x];
    __syncthreads();
    const int base  = s_ptr[0];
    const int total = s_ptr[RPB] - base;
    const int start = s_ptr[sub] - base;
    const int end_  = s_ptr[sub + 1] - base;

    float4 acc = {0.f, 0.f, 0.f, 0.f};
    for (int cb2 = 0; cb2 < total; cb2 += MAXE) {
        int cnt = total - cb2;
        if (cnt > MAXE) cnt = MAXE;
        for (int t = threadIdx.x; t < cnt; t += 256) {
            s_col[t] = csr_col[base + cb2 + t];
            s_val[t] = csr_val[base + cb2 + t];
        }
        __syncthreads();
        int js = start > cb2 ? start : cb2;
        int je = end_ < cb2 + cnt ? end_ : cb2 + cnt;
#pragma unroll 4
        for (int j = js; j < je; ++j) {
            const float v = s_val[j - cb2];
            const int   c = s_col[j - cb2];
            const ushort4 x = X[(size_t)c * NV4 + cb + lane];
            acc.x += v * bf2f(x.x);
            acc.y += v * bf2f(x.y);
            acc.z += v * bf2f(x.z);
            acc.w += v * bf2f(x.w);
        }
        __syncthreads();
    }
    const size_t oi = (size_t)r * NV4 + cb + lane;
    if (OUT_F32) {
        ((float4*)Yv)[oi] = acc;
    } else {
        ushort4 o;
        o.x = f2bf(acc.x); o.y = f2bf(acc.y); o.z = f2bf(acc.z); o.w = f2bf(acc.w);
        ((ushort4*)Yv)[oi] = o;
    }
}

// ---------- tiled transpose + bias: in [D, N] f32 -> out [N, D] f32 with +bias[d] ----------
__global__ __launch_bounds__(256) void transpose_bias_k(const float* __restrict__ in,
                                                        float* __restrict__ out,
                                                        const float* __restrict__ bias) {
    __shared__ float tile[32][33];
    int c0 = blockIdx.x * 32, r0 = blockIdx.y * 32;   // c over N, r over D
    int tx = threadIdx.x, ty = threadIdx.y;
#pragma unroll
    for (int i = ty; i < 32; i += 8)
        tile[i][tx] = in[(size_t)(r0 + i) * N_DIM + c0 + tx];
    __syncthreads();
    float b = bias[r0 + tx];
#pragma unroll
    for (int i = ty; i < 32; i += 8)
        out[(size_t)(c0 + i) * D_DIM + r0 + tx] = tile[tx][i] + b;
}

extern "C" void kernel_launch(void* const* d_in, const int* in_sizes, int n_in,
                              void* d_out, int out_size, void* d_ws, size_t ws_size,
                              hipStream_t stream) {
    const float* U    = (const float*)d_in[0];
    const float* bias = (const float*)d_in[1];
    const float* vals = (const float*)d_in[2];
    const int*   rows = (const int*)d_in[3];
    const int*   cols = (const int*)d_in[4];
    float* out = (float*)d_out;

    char* ws = (char*)d_ws;
    size_t off = 0;
    // A region: 16 MB. Holds UT/intermediate bf16 (8 MB) early, final f32 (16 MB) late.
    char* bufA = ws;                   off += (size_t)D_DIM * N_DIM * 4;
    int* row_ptr = (int*)(ws + off);   off += (size_t)K_F * (D_DIM + 1) * 4;
    off = (off + 15) & ~(size_t)15;
    int* cursor  = (int*)(ws + off);   off += (size_t)K_F * D_DIM * 4;
    int*   csr_col = (int*)(ws + off); off += (size_t)K_F * NNZ_F * 4;
    float* csr_val = (float*)(ws + off); off += (size_t)K_F * NNZ_F * 4;
    char* bufB = (char*)d_out;         // reuse output buffer (16 MB) as bf16 ping-pong

    const int grid_spmm = (D_DIM / RPB) * NCHUNK;

    // K1: transpose U -> A (bf16) + CSR count/scan (4 blocks), fused
    fused_t_build_k<<<T_TILES + K_F, 1024, 0, stream>>>(
        U, (unsigned short*)bufA, rows, row_ptr, cursor);

    // K2: scatter all factors
    scatter_all_k<<<K_F * (NNZ_F / 1024), 1024, 0, stream>>>(rows, cols, vals, cursor,
                                                             csr_col, csr_val);

    // K3: factor 3, A(bf16) -> B(bf16)
    spmm_chunk_k<false><<<grid_spmm, 256, 0, stream>>>(
        row_ptr + 3 * (D_DIM + 1), csr_col + 3 * (size_t)NNZ_F, csr_val + 3 * (size_t)NNZ_F,
        (const ushort4*)bufA, bufB);
    // K4: factor 2, B -> A (bf16)
    spmm_chunk_k<false><<<grid_spmm, 256, 0, stream>>>(
        row_ptr + 2 * (D_DIM + 1), csr_col + 2 * (size_t)NNZ_F, csr_val + 2 * (size_t)NNZ_F,
        (const ushort4*)bufB, bufA);
    // K5: factor 1, A -> B (bf16)
    spmm_chunk_k<false><<<grid_spmm, 256, 0, stream>>>(
        row_ptr + 1 * (D_DIM + 1), csr_col + 1 * (size_t)NNZ_F, csr_val + 1 * (size_t)NNZ_F,
        (const ushort4*)bufA, bufB);
    // K6: factor 0, B -> A (f32, 16 MB)
    spmm_chunk_k<true><<<grid_spmm, 256, 0, stream>>>(
        row_ptr + 0 * (D_DIM + 1), csr_col + 0 * (size_t)NNZ_F, csr_val + 0 * (size_t)NNZ_F,
        (const ushort4*)bufB, bufA);

    // K7: final transpose + bias, A(f32) -> out
    transpose_bias_k<<<dim3(N_DIM / 32, D_DIM / 32), dim3(32, 8), 0, stream>>>(
        (const float*)bufA, out, bias);
}

// Round 5
// 122.677 us; speedup vs baseline: 3.0991x; 1.1569x over previous
//
#include <hip/hip_runtime.h>

#define D_DIM 4096
#define N_DIM 1024
#define NNZ_F 131072
#define K_F 4
#define NCHUNK 8               // one column-chunk per XCD
#define LPR 16                 // lanes per row (16B each -> 128 cols)
#define RPB 16                 // rows per block (16 rows x 16 lanes = 256 thr)
#define MAXE 1024              // LDS staging capacity for CSR entries per block
#define XS8 (N_DIM / 8)        // 128 uint4-slots (8 bf16) per row
#define NV4 (N_DIM / 4)        // 256 float4 per row (f32 layout)

#define T_TILES ((D_DIM / 64) * (N_DIM / 64))   // 1024 transpose tiles

__device__ __forceinline__ unsigned short f2bf(float f) {
    union { float f; unsigned int u; } v; v.f = f;
    unsigned int r = v.u + 0x7fffu + ((v.u >> 16) & 1u);   // RNE, finite inputs
    return (unsigned short)(r >> 16);
}
__device__ __forceinline__ float bf_lo(unsigned int w) {
    return __uint_as_float(w << 16);
}
__device__ __forceinline__ float bf_hi(unsigned int w) {
    return __uint_as_float(w & 0xffff0000u);
}

// ---------- fused: transpose U [N,D] f32 -> UT [D,N] bf16  (+)  per-factor CSR count+scan
__global__ __launch_bounds__(1024) void fused_t_build_k(const float* __restrict__ in,
                                                        unsigned short* __restrict__ outb,
                                                        const int* __restrict__ rows,
                                                        int* __restrict__ row_ptr_g,
                                                        int* __restrict__ cursor_g) {
    __shared__ int s_cnt[4 * D_DIM];          // 64 KB: 4 sub-histograms OR transpose tile
    __shared__ int s_part[1024];
    const int tid = threadIdx.x;
    const int bid = blockIdx.x;

    if (bid < T_TILES) {
        // ---- transpose tile: 64x64, f32 in -> bf16 out ----
        float (*tile)[65] = (float (*)[65])s_cnt;
        const int gxi = bid & 63;            // tile along D
        const int gyi = bid >> 6;            // tile along N
        const int c0 = gxi * 64;             // offset in D
        const int r0 = gyi * 64;             // offset in N
        const int tx = tid & 63;
        const int ty = tid >> 6;             // 0..15
#pragma unroll
        for (int i = ty; i < 64; i += 16)
            tile[i][tx] = in[(size_t)(r0 + i) * D_DIM + c0 + tx];
        __syncthreads();
        const int px = (tid & 15) * 4;       // 4 n-locals per thread
        const int py = tid >> 4;             // 0..63 -> row of output tile
        ushort4 w;
        w.x = f2bf(tile[px + 0][py]);
        w.y = f2bf(tile[px + 1][py]);
        w.z = f2bf(tile[px + 2][py]);
        w.w = f2bf(tile[px + 3][py]);
        *(ushort4*)&outb[(size_t)(c0 + py) * N_DIM + r0 + px] = w;
        return;
    }

    // ---- CSR count + exclusive scan for factor f (one block per factor) ----
    const int f = bid - T_TILES;
    const int grp = (tid >> 8) & 3;          // 4 wave-groups, private histograms
#pragma unroll
    for (int k = 0; k < 16; ++k) s_cnt[tid + k * 1024] = 0;
    __syncthreads();

    int* h = s_cnt + grp * D_DIM;
    const int4* rp4 = (const int4*)(rows + (size_t)f * NNZ_F);
#pragma unroll 4
    for (int it = 0; it < NNZ_F / 4096; ++it) {      // 32 iters
        int4 r4 = rp4[(size_t)it * 1024 + tid];
        atomicAdd(&h[r4.x], 1);
        atomicAdd(&h[r4.y], 1);
        atomicAdd(&h[r4.z], 1);
        atomicAdd(&h[r4.w], 1);
    }
    __syncthreads();

    int c[4];
#pragma unroll
    for (int k = 0; k < 4; ++k)
        c[k] = s_cnt[tid * 4 + k] + s_cnt[D_DIM + tid * 4 + k]
             + s_cnt[2 * D_DIM + tid * 4 + k] + s_cnt[3 * D_DIM + tid * 4 + k];
    const int part = c[0] + c[1] + c[2] + c[3];
    s_part[tid] = part;
    __syncthreads();
    for (int off = 1; off < 1024; off <<= 1) {
        int v = (tid >= off) ? s_part[tid - off] : 0;
        __syncthreads();
        s_part[tid] += v;
        __syncthreads();
    }
    int excl = s_part[tid] - part;

    int* rp  = row_ptr_g + (size_t)f * (D_DIM + 1);
    int* cur = cursor_g + (size_t)f * D_DIM;
    int b = tid * 4;
#pragma unroll
    for (int k = 0; k < 4; ++k) {
        rp[b + k] = excl; cur[b + k] = excl; excl += c[k];
    }
    if (tid == 1023) rp[D_DIM] = NNZ_F;
}

// ---------- scatter all factors into CSR ----------
__global__ __launch_bounds__(1024) void scatter_all_k(const int* __restrict__ rows,
                                                      const int* __restrict__ cols,
                                                      const float* __restrict__ vals,
                                                      int* __restrict__ cursor,
                                                      int* __restrict__ csr_col,
                                                      float* __restrict__ csr_val) {
    const int f = blockIdx.x >> 7;                        // 128 blocks per factor
    const size_t j = (size_t)(blockIdx.x & 127) * 1024 + threadIdx.x;
    const size_t base = (size_t)f * NNZ_F;
    int r = rows[base + j];
    int p = atomicAdd(&cursor[(size_t)f * D_DIM + r], 1);
    csr_col[base + p] = cols[base + j];
    csr_val[base + p] = vals[base + j];
}

// ---------- chunked CSR spmm, bf16 input, 16B gathers ----------
// chunk = blockIdx & 7 -> XCD-affine; each XCD's L2 holds its 1MB bf16 column slice.
// 16 rows/block, 16 lanes/row, each lane: one uint4 (8 bf16 cols) per nnz.
template <bool OUT_F32>
__global__ __launch_bounds__(256) void spmm_chunk_k(const int* __restrict__ row_ptr,
                                                    const int* __restrict__ csr_col,
                                                    const float* __restrict__ csr_val,
                                                    const uint4* __restrict__ X,
                                                    void* __restrict__ Yv) {
    const int chunk = blockIdx.x & (NCHUNK - 1);
    const int rg    = blockIdx.x >> 3;
    const int r0    = rg * RPB;
    const int sub   = threadIdx.x >> 4;       // row within group: 0..15
    const int lane  = threadIdx.x & 15;       // uint4 slot within chunk
    const int cb8   = chunk * LPR;            // chunk base in uint4 slots
    const int r     = r0 + sub;

    __shared__ int   s_ptr[RPB + 1];
    __shared__ int   s_col[MAXE];
    __shared__ float s_val[MAXE];

    if (threadIdx.x <= RPB) s_ptr[threadIdx.x] = row_ptr[r0 + threadIdx.x];
    __syncthreads();
    const int base  = s_ptr[0];
    const int total = s_ptr[RPB] - base;
    const int start = s_ptr[sub] - base;
    const int end_  = s_ptr[sub + 1] - base;

    float acc[8];
#pragma unroll
    for (int k = 0; k < 8; ++k) acc[k] = 0.f;

    const int slot = cb8 + lane;
    for (int cb2 = 0; cb2 < total; cb2 += MAXE) {
        int cnt = total - cb2;
        if (cnt > MAXE) cnt = MAXE;
        for (int t = threadIdx.x; t < cnt; t += 256) {
            s_col[t] = csr_col[base + cb2 + t];
            s_val[t] = csr_val[base + cb2 + t];
        }
        __syncthreads();
        int js = start > cb2 ? start : cb2;
        int je = end_ < cb2 + cnt ? end_ : cb2 + cnt;
        if (js < je) {
            // 2-deep software pipeline: preload next entry while accumulating current
            int   jj = js - cb2;
            uint4 x  = X[(size_t)s_col[jj] * XS8 + slot];
            float v  = s_val[jj];
#pragma unroll 2
            for (int j = js + 1; j < je; ++j) {
                const int   jn = j - cb2;
                const uint4 xn = X[(size_t)s_col[jn] * XS8 + slot];
                const float vn = s_val[jn];
                acc[0] += v * bf_lo(x.x);
                acc[1] += v * bf_hi(x.x);
                acc[2] += v * bf_lo(x.y);
                acc[3] += v * bf_hi(x.y);
                acc[4] += v * bf_lo(x.z);
                acc[5] += v * bf_hi(x.z);
                acc[6] += v * bf_lo(x.w);
                acc[7] += v * bf_hi(x.w);
                x = xn; v = vn;
            }
            acc[0] += v * bf_lo(x.x);
            acc[1] += v * bf_hi(x.x);
            acc[2] += v * bf_lo(x.y);
            acc[3] += v * bf_hi(x.y);
            acc[4] += v * bf_lo(x.z);
            acc[5] += v * bf_hi(x.z);
            acc[6] += v * bf_lo(x.w);
            acc[7] += v * bf_hi(x.w);
        }
        __syncthreads();
    }

    if (OUT_F32) {
        float4* Y = (float4*)Yv;
        const size_t oi = (size_t)r * NV4 + (size_t)(cb8 + lane) * 2;
        Y[oi]     = make_float4(acc[0], acc[1], acc[2], acc[3]);
        Y[oi + 1] = make_float4(acc[4], acc[5], acc[6], acc[7]);
    } else {
        uint4 o;
        o.x = (unsigned int)f2bf(acc[0]) | ((unsigned int)f2bf(acc[1]) << 16);
        o.y = (unsigned int)f2bf(acc[2]) | ((unsigned int)f2bf(acc[3]) << 16);
        o.z = (unsigned int)f2bf(acc[4]) | ((unsigned int)f2bf(acc[5]) << 16);
        o.w = (unsigned int)f2bf(acc[6]) | ((unsigned int)f2bf(acc[7]) << 16);
        ((uint4*)Yv)[(size_t)r * XS8 + slot] = o;
    }
}

// ---------- tiled transpose + bias: in [D, N] f32 -> out [N, D] f32 with +bias[d] ----------
__global__ __launch_bounds__(256) void transpose_bias_k(const float* __restrict__ in,
                                                        float* __restrict__ out,
                                                        const float* __restrict__ bias) {
    __shared__ float tile[32][33];
    int c0 = blockIdx.x * 32, r0 = blockIdx.y * 32;   // c over N, r over D
    int tx = threadIdx.x, ty = threadIdx.y;
#pragma unroll
    for (int i = ty; i < 32; i += 8)
        tile[i][tx] = in[(size_t)(r0 + i) * N_DIM + c0 + tx];
    __syncthreads();
    float b = bias[r0 + tx];
#pragma unroll
    for (int i = ty; i < 32; i += 8)
        out[(size_t)(c0 + i) * D_DIM + r0 + tx] = tile[tx][i] + b;
}

extern "C" void kernel_launch(void* const* d_in, const int* in_sizes, int n_in,
                              void* d_out, int out_size, void* d_ws, size_t ws_size,
                              hipStream_t stream) {
    const float* U    = (const float*)d_in[0];
    const float* bias = (const float*)d_in[1];
    const float* vals = (const float*)d_in[2];
    const int*   rows = (const int*)d_in[3];
    const int*   cols = (const int*)d_in[4];
    float* out = (float*)d_out;

    char* ws = (char*)d_ws;
    size_t off = 0;
    // A region: 16 MB. Holds UT/intermediate bf16 (8 MB) early, final f32 (16 MB) late.
    char* bufA = ws;                   off += (size_t)D_DIM * N_DIM * 4;
    int* row_ptr = (int*)(ws + off);   off += (size_t)K_F * (D_DIM + 1) * 4;
    off = (off + 15) & ~(size_t)15;
    int* cursor  = (int*)(ws + off);   off += (size_t)K_F * D_DIM * 4;
    int*   csr_col = (int*)(ws + off); off += (size_t)K_F * NNZ_F * 4;
    float* csr_val = (float*)(ws + off); off += (size_t)K_F * NNZ_F * 4;
    char* bufB = (char*)d_out;         // reuse output buffer (16 MB) as bf16 ping-pong

    const int grid_spmm = (D_DIM / RPB) * NCHUNK;   // 256 * 8 = 2048 blocks

    // K1: transpose U -> A (bf16) + CSR count/scan (4 blocks), fused
    fused_t_build_k<<<T_TILES + K_F, 1024, 0, stream>>>(
        U, (unsigned short*)bufA, rows, row_ptr, cursor);

    // K2: scatter all factors
    scatter_all_k<<<K_F * (NNZ_F / 1024), 1024, 0, stream>>>(rows, cols, vals, cursor,
                                                             csr_col, csr_val);

    // K3: factor 3, A(bf16) -> B(bf16)
    spmm_chunk_k<false><<<grid_spmm, 256, 0, stream>>>(
        row_ptr + 3 * (D_DIM + 1), csr_col + 3 * (size_t)NNZ_F, csr_val + 3 * (size_t)NNZ_F,
        (const uint4*)bufA, bufB);
    // K4: factor 2, B -> A (bf16)
    spmm_chunk_k<false><<<grid_spmm, 256, 0, stream>>>(
        row_ptr + 2 * (D_DIM + 1), csr_col + 2 * (size_t)NNZ_F, csr_val + 2 * (size_t)NNZ_F,
        (const uint4*)bufB, bufA);
    // K5: factor 1, A -> B (bf16)
    spmm_chunk_k<false><<<grid_spmm, 256, 0, stream>>>(
        row_ptr + 1 * (D_DIM + 1), csr_col + 1 * (size_t)NNZ_F, csr_val + 1 * (size_t)NNZ_F,
        (const uint4*)bufA, bufB);
    // K6: factor 0, B -> A (f32, 16 MB)
    spmm_chunk_k<true><<<grid_spmm, 256, 0, stream>>>(
        row_ptr + 0 * (D_DIM + 1), csr_col + 0 * (size_t)NNZ_F, csr_val + 0 * (size_t)NNZ_F,
        (const uint4*)bufB, bufA);

    // K7: final transpose + bias, A(f32) -> out
    transpose_bias_k<<<dim3(N_DIM / 32, D_DIM / 32), dim3(32, 8), 0, stream>>>(
        (const float*)bufA, out, bias);
}